// Round 1
// baseline (266.848 us; speedup 1.0000x reference)
//
#include <hip/hip_runtime.h>
#include <hip/hip_bf16.h>
#include <stdint.h>

#define Bb 2
#define Ss 2048
#define Dd 1024
#define Hh 16

typedef __hip_bfloat16 bf16;
typedef __attribute__((ext_vector_type(8))) short bf16x8;
typedef __attribute__((ext_vector_type(4))) short short4v;
typedef __attribute__((ext_vector_type(4))) float f32x4;
typedef __attribute__((ext_vector_type(4))) unsigned uint4v;
typedef __attribute__((ext_vector_type(2))) unsigned uint2v;

__device__ __forceinline__ void gl_lds16(const void* g, void* l) {
  __builtin_amdgcn_global_load_lds((const __attribute__((address_space(1))) void*)g,
                                   (__attribute__((address_space(3))) void*)l, 16, 0, 0);
}

// two f32 -> packed bf16 pair, round-half-up
__device__ __forceinline__ unsigned pack2(float a, float b) {
  unsigned ua = __builtin_bit_cast(unsigned, a), ub = __builtin_bit_cast(unsigned, b);
  return ((ua + 0x8000u) >> 16) | ((ub + 0x8000u) & 0xffff0000u);
}

// hardware packed f32->bf16 (RNE), 1 VALU op (T12 recipe; no builtin on gfx950)
__device__ __forceinline__ unsigned cvtpk2(float a, float b) {
  unsigned r;
  asm("v_cvt_pk_bf16_f32 %0, %1, %2" : "=v"(r) : "v"(a), "v"(b));
  return r;
}

// rows are 128B (8 chunks of 16B); logical chunk cl is XOR-swizzled by (row&7)
__device__ __forceinline__ bf16x8 lds_frag(const char* base, int row, int cl) {
  int phys = cl ^ (row & 7);
  return *(const bf16x8*)(base + row * 128 + phys * 16);
}

// ---------------- q,k fp32 -> bf16 (streaming) ----------------
__global__ void convert_qk(const float* __restrict__ q, const float* __restrict__ k,
                           bf16* __restrict__ Qb, bf16* __restrict__ Kb) {
  int sel = blockIdx.x >> 11;
  const float* src = sel ? k : q;
  bf16* dst = sel ? Kb : Qb;
  size_t i = (size_t)(blockIdx.x & 2047) * 256 + threadIdx.x;
  f32x4 v0 = *(const f32x4*)(src + i * 8);
  f32x4 v1 = *(const f32x4*)(src + i * 8 + 4);
  uint4v o = {pack2(v0[0], v0[1]), pack2(v0[2], v0[3]),
              pack2(v1[0], v1[1]), pack2(v1[2], v1[3])};
  *(uint4v*)((char*)dst + i * 16) = o;
}

// ---------------- weight transpose: fp32 [1024,1024] -> bf16 W^T ----------------
__global__ void transpose_w4(const float* w0, const float* w1, const float* w2, const float* w3,
                             bf16* t0, bf16* t1, bf16* t2, bf16* t3) {
  const float* W;
  bf16* T;
  switch (blockIdx.z) {
    case 0: W = w0; T = t0; break;
    case 1: W = w1; T = t1; break;
    case 2: W = w2; T = t2; break;
    default: W = w3; T = t3; break;
  }
  __shared__ bf16 tile[64][65];
  int tx = threadIdx.x, ty = threadIdx.y;
  int r0 = blockIdx.y * 64, c0 = blockIdx.x * 64;
#pragma unroll
  for (int j = 0; j < 16; j++) {
    int r = ty + j * 4;
    tile[r][tx] = __float2bfloat16(W[(size_t)(r0 + r) * 1024 + c0 + tx]);
  }
  __syncthreads();
#pragma unroll
  for (int j = 0; j < 16; j++) {
    int r = ty + j * 4;
    T[(size_t)(c0 + r) * 1024 + r0 + tx] = tile[tx][r];
  }
}

// ---------------- merged QKV GEMM (frozen from round 9) ----------------
#define SCL 0.180336878f
__global__ __launch_bounds__(256, 3) void gemm_qkv(
    const bf16* __restrict__ Qb, const bf16* __restrict__ Kb, const float* __restrict__ v,
    const bf16* __restrict__ WTall,
    const float* __restrict__ bq, const float* __restrict__ bk, const float* __restrict__ bv,
    bf16* __restrict__ Qp, bf16* __restrict__ Kp, bf16* __restrict__ Vt) {
  __shared__ char As[128 * 128], Bs[128 * 128];
  const int K = 1024;
  int tid = threadIdx.x, lane = tid & 63, w = tid >> 6;
  int quad = lane >> 4, l16 = lane & 15;
  int xcd = blockIdx.x & 7, slot = blockIdx.x >> 3;
  int pair = xcd * 12 + (slot % 12);
  int nloc_blk = slot / 12;
  int mblk = pair / 3, sel = pair % 3;
  int m0 = mblk * 128;
  int nloc0 = nloc_blk * 128;
  int n0 = sel * 1024 + nloc0;
  const bf16* Ab = (sel == 0) ? Qb : Kb;
  const float* bias = (sel == 0) ? bq : (sel == 1) ? bk : bv;
  int wm = (w >> 1) * 64, wn = (w & 1) * 64;
  f32x4 acc[4][4] = {};
  for (int k0 = 0; k0 < K; k0 += 64) {
    __syncthreads();
    if (sel < 2) {
#pragma unroll
      for (int i = 0; i < 4; i++) {
        int c = i * 256 + tid;
        int row = c >> 3, cc = c & 7;
        int g = (cc ^ (row & 7)) * 16;
        gl_lds16((const char*)Ab + ((size_t)(m0 + row) * K + k0) * 2 + g, As + c * 16);
        gl_lds16((const char*)WTall + ((size_t)(n0 + row) * K + k0) * 2 + g, Bs + c * 16);
      }
    } else {
#pragma unroll
      for (int i = 0; i < 4; i++) {
        int c = i * 256 + tid;
        int row = c >> 3, cc = c & 7;
        int g = cc ^ (row & 7);
        const float* src = v + (size_t)(m0 + row) * K + k0 + g * 8;
        f32x4 v0 = *(const f32x4*)src;
        f32x4 v1 = *(const f32x4*)(src + 4);
        uint4v o = {pack2(v0[0], v0[1]), pack2(v0[2], v0[3]),
                    pack2(v1[0], v1[1]), pack2(v1[2], v1[3])};
        *(uint4v*)(As + c * 16) = o;
        gl_lds16((const char*)WTall + ((size_t)(n0 + row) * K + k0) * 2 + g * 16, Bs + c * 16);
      }
    }
    __syncthreads();
#pragma unroll
    for (int ks = 0; ks < 2; ks++) {
      bf16x8 a[4], b[4];
#pragma unroll
      for (int mt = 0; mt < 4; mt++) a[mt] = lds_frag(As, wm + mt * 16 + l16, ks * 4 + quad);
#pragma unroll
      for (int nt = 0; nt < 4; nt++) b[nt] = lds_frag(Bs, wn + nt * 16 + l16, ks * 4 + quad);
#pragma unroll
      for (int mt = 0; mt < 4; mt++)
#pragma unroll
        for (int nt = 0; nt < 4; nt++)
          acc[mt][nt] = __builtin_amdgcn_mfma_f32_16x16x32_bf16(a[mt], b[nt], acc[mt][nt], 0, 0, 0);
    }
  }
#pragma unroll
  for (int nt = 0; nt < 4; nt++) {
    int nloc = nloc0 + wn + nt * 16 + l16;
    float bvv = bias[nloc];
#pragma unroll
    for (int mt = 0; mt < 4; mt++) {
      int row = m0 + wm + mt * 16 + quad * 4;
      if (sel == 2) {
        int d = nloc & 63, h = nloc >> 6;
        int b_ = row >> 11, s = row & 2047;
        int bh = b_ * 16 + h;
        float f0 = acc[mt][nt][0] + bvv, f1 = acc[mt][nt][1] + bvv;
        float f2 = acc[mt][nt][2] + bvv, f3 = acc[mt][nt][3] + bvv;
        uint2v pv = {pack2(f0, f1), pack2(f2, f3)};
        *(uint2v*)((char*)Vt + ((size_t)(bh * 64 + d) * Ss + s) * 2) = pv;
      } else {
        bf16* C = (sel == 0) ? Qp : Kp;
        float scale = (sel == 0) ? SCL : 1.0f;
#pragma unroll
        for (int r = 0; r < 4; r++)
          C[(size_t)(row + r) * 1024 + nloc] = __float2bfloat16((acc[mt][nt][r] + bvv) * scale);
      }
    }
  }
}

// ---------------- flash attention ----------------
// 512 threads, 8 waves: (w&3) = 32-q group, (w>>2) = kb parity.
// Round-10 pipeline rebuild (T3/T4/T5 + Q-hoist + cvt_pk):
//  - Q lives in registers (16 VGPR/lane), never in LDS
//  - K/V LDS double-buffered: buf[d] = 32K {Ks0,Vs0,Ks1,Vs1}, 64K total
//    -> still 2 blocks/CU (128K of 160K), 4 waves/SIMD
//  - prefetch kb-pair t+1 before computing t; counted s_waitcnt vmcnt(4)
//    + raw s_barrier (never drains the prefetch, unlike __syncthreads)
//  - P f32->bf16 via v_cvt_pk_bf16_f32 (1 op / 2 vals vs 5 for pack2)
//  - s_setprio(1) around MFMA clusters (phase-split now exists -> T5 applies)
// P never touches LDS: S^T C-layout (row=quad*4+reg=k, col=lane&15=q) IS the
// A-layout of mfma_f32_16x16x16_bf16 -> PV straight from regs.
__global__ __launch_bounds__(512, 4) void flash_attn(
    const bf16* __restrict__ Q, const bf16* __restrict__ Kp,
    const bf16* __restrict__ Vt, bf16* __restrict__ O) {
  __shared__ char lds[64 * 1024];
  int tid = threadIdx.x, lane = tid & 63, w = tid >> 6;
  int quad = lane >> 4, l16 = lane & 15;
  int bx = blockIdx.x;
  int bh = bx & 31, b = bh >> 4, h = bh & 15;
  int q0 = (bx >> 5) * 128;
  int qw = (w & 3) * 32;
  int parity = w >> 2;

  // stage one kb-pair (K + V tiles for both parities) into buffer dsel
  auto stage = [&](int dsel, int kb0) {
    int row = tid >> 3, cc = tid & 7;
    int gcol = (cc ^ (row & 7)) * 16;
#pragma unroll
    for (int i = 0; i < 4; i++) {
      int kbb = kb0 + (i >> 1);
      char* dst = lds + dsel * 32 * 1024 + i * 8 * 1024 + tid * 16;
      if ((i & 1) == 0)
        gl_lds16((const char*)Kp + ((size_t)(b * Ss + kbb * 64 + row) * Dd + h * 64) * 2 + gcol, dst);
      else
        gl_lds16((const char*)Vt + ((size_t)(bh * 64 + row) * Ss + kbb * 64) * 2 + gcol, dst);
    }
  };

  stage(0, 0);                       // prologue: fill buf0
  asm volatile("" ::: "memory");     // keep prologue loads oldest in vmcnt order

  // Q -> registers: qf[qt][ks] == old lds_frag(Qlds, qw+qt*16+l16, ks*4+quad)
  bf16x8 qf[2][2];
#pragma unroll
  for (int qt = 0; qt < 2; qt++)
#pragma unroll
    for (int ks = 0; ks < 2; ks++) {
      int qrow = q0 + qw + qt * 16 + l16;
      qf[qt][ks] = *(const bf16x8*)((const char*)Q +
          ((size_t)(b * Ss + qrow) * Dd + h * 64 + (ks * 4 + quad) * 8) * 2);
    }

  f32x4 o_acc[2][4] = {};
  f32x4 l_acc[2] = {};
  const short4v ones4 = {(short)0x3F80, (short)0x3F80, (short)0x3F80, (short)0x3F80};

  const int NT = Ss / 128;  // 16 kb-pair iterations
  for (int it = 0; it < NT; ++it) {
    int cur = it & 1;
    if (it < NT - 1) {
      stage(cur ^ 1, (it + 1) * 2);                    // prefetch next pair
      asm volatile("s_waitcnt vmcnt(4)" ::: "memory"); // my buf[cur] loads done
    } else {
      asm volatile("s_waitcnt vmcnt(0)" ::: "memory");
    }
    __builtin_amdgcn_s_barrier();                      // everyone's buf[cur] done
    asm volatile("" ::: "memory");

    const char* Ksb = lds + cur * 32 * 1024 + parity * 16 * 1024;
    const char* Vsb = Ksb + 8 * 1024;

    // S^T = K @ Q^T : s[kt][qt], k = kt*16+quad*4+reg, q = qw+qt*16+l16
    f32x4 s[4][2] = {};
#pragma unroll
    for (int ks = 0; ks < 2; ks++) {
      bf16x8 ak[4];
#pragma unroll
      for (int kt = 0; kt < 4; kt++) ak[kt] = lds_frag(Ksb, kt * 16 + l16, ks * 4 + quad);
      __builtin_amdgcn_s_setprio(1);
#pragma unroll
      for (int kt = 0; kt < 4; kt++)
#pragma unroll
        for (int qt = 0; qt < 2; qt++)
          s[kt][qt] = __builtin_amdgcn_mfma_f32_16x16x32_bf16(ak[kt], qf[qt][ks], s[kt][qt], 0, 0, 0);
      __builtin_amdgcn_s_setprio(0);
    }

    // exp2 -> A-frags in registers -> PV + l via K=16 MFMA (no P LDS round-trip)
#pragma unroll
    for (int kt = 0; kt < 4; kt++) {
      short4v af[2];
#pragma unroll
      for (int qt = 0; qt < 2; qt++) {
        union { short4v s4; uint2v u2; } u;
        u.u2[0] = cvtpk2(exp2f(s[kt][qt][0]), exp2f(s[kt][qt][1]));
        u.u2[1] = cvtpk2(exp2f(s[kt][qt][2]), exp2f(s[kt][qt][3]));
        af[qt] = u.s4;
      }
      __builtin_amdgcn_s_setprio(1);
#pragma unroll
      for (int nt = 0; nt < 4; nt++) {
        // B-frag: B[k=kt*16+quad*4+i][n=nt*16+l16] = Vs[row=n][col=k]
        int row = nt * 16 + l16;
        int chunk = kt * 2 + (quad >> 1);
        int addr = row * 128 + ((chunk ^ (row & 7)) * 16) + (quad & 1) * 8;
        short4v bfv = *(const short4v*)(Vsb + addr);
#pragma unroll
        for (int qt = 0; qt < 2; qt++)
          o_acc[qt][nt] = __builtin_amdgcn_mfma_f32_16x16x16bf16_1k(af[qt], bfv, o_acc[qt][nt], 0, 0, 0);
      }
#pragma unroll
      for (int qt = 0; qt < 2; qt++)
        l_acc[qt] = __builtin_amdgcn_mfma_f32_16x16x16bf16_1k(af[qt], ones4, l_acc[qt], 0, 0, 0);
      __builtin_amdgcn_s_setprio(0);
    }

    asm volatile("" ::: "memory");
    __builtin_amdgcn_s_barrier();   // all waves done reading buf[cur]
  }

  // merge parity partials (additive), normalize, write
  __syncthreads();
  float* Obuf = (float*)lds;                 // [128][64] f32 = 32K (buf0 dead)
  float* Lbuf = (float*)(lds + 32 * 1024);   // [128] f32 (buf1 dead)
  if (parity == 1) {
#pragma unroll
    for (int qt = 0; qt < 2; qt++)
#pragma unroll
      for (int r = 0; r < 4; r++) {
        int qrow = qw + qt * 16 + quad * 4 + r;
#pragma unroll
        for (int nt = 0; nt < 4; nt++) Obuf[qrow * 64 + nt * 16 + l16] = o_acc[qt][nt][r];
        Lbuf[qrow] = l_acc[qt][r];
      }
  }
  __syncthreads();
  if (parity == 0) {
#pragma unroll
    for (int qt = 0; qt < 2; qt++)
#pragma unroll
      for (int r = 0; r < 4; r++) {
        int qrow = qw + qt * 16 + quad * 4 + r;
        float inv = 1.0f / (l_acc[qt][r] + Lbuf[qrow]);
        int grow = b * Ss + q0 + qrow;
#pragma unroll
        for (int nt = 0; nt < 4; nt++) {
          float val = (o_acc[qt][nt][r] + Obuf[qrow * 64 + nt * 16 + l16]) * inv;
          O[(size_t)grow * Dd + h * 64 + nt * 16 + l16] = __float2bfloat16(val);
        }
      }
  }
}

// ---------------- output GEMM: 64x64 tiles, 1024 blocks (4/CU) ----------------
__global__ __launch_bounds__(256, 4) void gemm_out(
    const bf16* __restrict__ AO, const bf16* __restrict__ WT,
    const float* __restrict__ bo, float* __restrict__ out) {
  __shared__ char As[64 * 128], Bs[64 * 128];
  const int K = 1024;
  int tid = threadIdx.x, lane = tid & 63, w = tid >> 6;
  int quad = lane >> 4, l16 = lane & 15;
  int xcd = blockIdx.x & 7, slot = blockIdx.x >> 3;  // 0..127
  int mblk = xcd * 8 + (slot & 7);                   // 0..63
  int nblk = slot >> 3;                              // 0..15
  int m0 = mblk * 64, n0 = nblk * 64;
  int wm = (w & 1) * 32, wn = (w >> 1) * 32;
  f32x4 acc[2][2] = {};
  for (int k0 = 0; k0 < K; k0 += 64) {
    __syncthreads();
#pragma unroll
    for (int i = 0; i < 2; i++) {
      int c = i * 256 + tid;
      int row = c >> 3, cc = c & 7;
      int g = (cc ^ (row & 7)) * 16;
      gl_lds16((const char*)AO + ((size_t)(m0 + row) * K + k0) * 2 + g, As + c * 16);
      gl_lds16((const char*)WT + ((size_t)(n0 + row) * K + k0) * 2 + g, Bs + c * 16);
    }
    __syncthreads();
#pragma unroll
    for (int ks = 0; ks < 2; ks++) {
      bf16x8 a[2], b[2];
#pragma unroll
      for (int mt = 0; mt < 2; mt++) a[mt] = lds_frag(As, wm + mt * 16 + l16, ks * 4 + quad);
#pragma unroll
      for (int nt = 0; nt < 2; nt++) b[nt] = lds_frag(Bs, wn + nt * 16 + l16, ks * 4 + quad);
#pragma unroll
      for (int mt = 0; mt < 2; mt++)
#pragma unroll
        for (int nt = 0; nt < 2; nt++)
          acc[mt][nt] = __builtin_amdgcn_mfma_f32_16x16x32_bf16(a[mt], b[nt], acc[mt][nt], 0, 0, 0);
    }
  }
#pragma unroll
  for (int nt = 0; nt < 2; nt++) {
    int col = n0 + wn + nt * 16 + l16;
    float bvv = bo[col];
#pragma unroll
    for (int mt = 0; mt < 2; mt++) {
      int row = m0 + wm + mt * 16 + quad * 4;
#pragma unroll
      for (int r = 0; r < 4; r++)
        out[(size_t)(row + r) * 1024 + col] = acc[mt][nt][r] + bvv;
    }
  }
}

extern "C" void kernel_launch(void* const* d_in, const int* in_sizes, int n_in,
                              void* d_out, int out_size, void* d_ws, size_t ws_size,
                              hipStream_t stream) {
  const float* q  = (const float*)d_in[0];
  const float* k  = (const float*)d_in[1];
  const float* v  = (const float*)d_in[2];
  const float* wq = (const float*)d_in[3];
  const float* bq = (const float*)d_in[4];
  const float* wk = (const float*)d_in[5];
  const float* bk = (const float*)d_in[6];
  const float* wv = (const float*)d_in[7];
  const float* bv = (const float*)d_in[8];
  const float* wo = (const float*)d_in[9];
  const float* bo = (const float*)d_in[10];
  float* out = (float*)d_out;

  // ws: 32 MB.  0-6: wt_qkv  6-8: wto  8-16: Qp->AO  16-24: Kp  24-32: Vt
  // d_out doubles as scratch: Qb (0-8), Kb (8-16) bf16 — dead before gemm_out.
  char* ws = (char*)d_ws;
  const size_t MB = (size_t)1024 * 1024;
  bf16* wtall = (bf16*)(ws + 0 * MB);
  bf16* wtq = wtall;
  bf16* wtk = (bf16*)(ws + 2 * MB);
  bf16* wtv = (bf16*)(ws + 4 * MB);
  bf16* wto = (bf16*)(ws + 6 * MB);
  bf16* Qp  = (bf16*)(ws + 8 * MB);
  bf16* AO  = Qp;
  bf16* Kp  = (bf16*)(ws + 16 * MB);
  bf16* Vt  = (bf16*)(ws + 24 * MB);
  bf16* Qb  = (bf16*)((char*)d_out + 0 * MB);
  bf16* Kb  = (bf16*)((char*)d_out + 8 * MB);

  dim3 tb(64, 4);
  convert_qk<<<4096, 256, 0, stream>>>(q, k, Qb, Kb);
  transpose_w4<<<dim3(16, 16, 4), tb, 0, stream>>>(wq, wk, wv, wo, wtq, wtk, wtv, wto);
  gemm_qkv<<<768, 256, 0, stream>>>(Qb, Kb, v, wtall, bq, bk, bv, Qp, Kp, Vt);
  flash_attn<<<512, 512, 0, stream>>>(Qp, Kp, Vt, AO);
  gemm_out<<<1024, 256, 0, stream>>>(AO, wto, bo, out);
}

// Round 4
// 248.916 us; speedup vs baseline: 1.0720x; 1.0720x over previous
//
#include <hip/hip_runtime.h>
#include <hip/hip_bf16.h>
#include <stdint.h>

#define Bb 2
#define Ss 2048
#define Dd 1024
#define Hh 16

typedef __hip_bfloat16 bf16;
typedef __attribute__((ext_vector_type(8))) short bf16x8;
typedef __attribute__((ext_vector_type(4))) short short4v;
typedef __attribute__((ext_vector_type(4))) float f32x4;
typedef __attribute__((ext_vector_type(4))) unsigned uint4v;
typedef __attribute__((ext_vector_type(2))) unsigned uint2v;

__device__ __forceinline__ void gl_lds16(const void* g, void* l) {
  __builtin_amdgcn_global_load_lds((const __attribute__((address_space(1))) void*)g,
                                   (__attribute__((address_space(3))) void*)l, 16, 0, 0);
}

// two f32 -> packed bf16 pair, round-half-up
__device__ __forceinline__ unsigned pack2(float a, float b) {
  unsigned ua = __builtin_bit_cast(unsigned, a), ub = __builtin_bit_cast(unsigned, b);
  return ((ua + 0x8000u) >> 16) | ((ub + 0x8000u) & 0xffff0000u);
}

// rows are 128B (8 chunks of 16B); logical chunk cl is XOR-swizzled by (row&7)
__device__ __forceinline__ bf16x8 lds_frag(const char* base, int row, int cl) {
  int phys = cl ^ (row & 7);
  return *(const bf16x8*)(base + row * 128 + phys * 16);
}

// ---------------- q,k fp32 -> bf16 (streaming) ----------------
__global__ void convert_qk(const float* __restrict__ q, const float* __restrict__ k,
                           bf16* __restrict__ Qb, bf16* __restrict__ Kb) {
  int sel = blockIdx.x >> 11;
  const float* src = sel ? k : q;
  bf16* dst = sel ? Kb : Qb;
  size_t i = (size_t)(blockIdx.x & 2047) * 256 + threadIdx.x;
  f32x4 v0 = *(const f32x4*)(src + i * 8);
  f32x4 v1 = *(const f32x4*)(src + i * 8 + 4);
  uint4v o = {pack2(v0[0], v0[1]), pack2(v0[2], v0[3]),
              pack2(v1[0], v1[1]), pack2(v1[2], v1[3])};
  *(uint4v*)((char*)dst + i * 16) = o;
}

// ---------------- weight transpose: fp32 [1024,1024] -> bf16 W^T ----------------
__global__ void transpose_w4(const float* w0, const float* w1, const float* w2, const float* w3,
                             bf16* t0, bf16* t1, bf16* t2, bf16* t3) {
  const float* W;
  bf16* T;
  switch (blockIdx.z) {
    case 0: W = w0; T = t0; break;
    case 1: W = w1; T = t1; break;
    case 2: W = w2; T = t2; break;
    default: W = w3; T = t3; break;
  }
  __shared__ bf16 tile[64][65];
  int tx = threadIdx.x, ty = threadIdx.y;
  int r0 = blockIdx.y * 64, c0 = blockIdx.x * 64;
#pragma unroll
  for (int j = 0; j < 16; j++) {
    int r = ty + j * 4;
    tile[r][tx] = __float2bfloat16(W[(size_t)(r0 + r) * 1024 + c0 + tx]);
  }
  __syncthreads();
#pragma unroll
  for (int j = 0; j < 16; j++) {
    int r = ty + j * 4;
    T[(size_t)(c0 + r) * 1024 + r0 + tx] = tile[tx][r];
  }
}

// ---------------- merged QKV GEMM (frozen from round 9) ----------------
#define SCL 0.180336878f
__global__ __launch_bounds__(256, 3) void gemm_qkv(
    const bf16* __restrict__ Qb, const bf16* __restrict__ Kb, const float* __restrict__ v,
    const bf16* __restrict__ WTall,
    const float* __restrict__ bq, const float* __restrict__ bk, const float* __restrict__ bv,
    bf16* __restrict__ Qp, bf16* __restrict__ Kp, bf16* __restrict__ Vt) {
  __shared__ char As[128 * 128], Bs[128 * 128];
  const int K = 1024;
  int tid = threadIdx.x, lane = tid & 63, w = tid >> 6;
  int quad = lane >> 4, l16 = lane & 15;
  int xcd = blockIdx.x & 7, slot = blockIdx.x >> 3;
  int pair = xcd * 12 + (slot % 12);
  int nloc_blk = slot / 12;
  int mblk = pair / 3, sel = pair % 3;
  int m0 = mblk * 128;
  int nloc0 = nloc_blk * 128;
  int n0 = sel * 1024 + nloc0;
  const bf16* Ab = (sel == 0) ? Qb : Kb;
  const float* bias = (sel == 0) ? bq : (sel == 1) ? bk : bv;
  int wm = (w >> 1) * 64, wn = (w & 1) * 64;
  f32x4 acc[4][4] = {};
  for (int k0 = 0; k0 < K; k0 += 64) {
    __syncthreads();
    if (sel < 2) {
#pragma unroll
      for (int i = 0; i < 4; i++) {
        int c = i * 256 + tid;
        int row = c >> 3, cc = c & 7;
        int g = (cc ^ (row & 7)) * 16;
        gl_lds16((const char*)Ab + ((size_t)(m0 + row) * K + k0) * 2 + g, As + c * 16);
        gl_lds16((const char*)WTall + ((size_t)(n0 + row) * K + k0) * 2 + g, Bs + c * 16);
      }
    } else {
#pragma unroll
      for (int i = 0; i < 4; i++) {
        int c = i * 256 + tid;
        int row = c >> 3, cc = c & 7;
        int g = cc ^ (row & 7);
        const float* src = v + (size_t)(m0 + row) * K + k0 + g * 8;
        f32x4 v0 = *(const f32x4*)src;
        f32x4 v1 = *(const f32x4*)(src + 4);
        uint4v o = {pack2(v0[0], v0[1]), pack2(v0[2], v0[3]),
                    pack2(v1[0], v1[1]), pack2(v1[2], v1[3])};
        *(uint4v*)(As + c * 16) = o;
        gl_lds16((const char*)WTall + ((size_t)(n0 + row) * K + k0) * 2 + g * 16, Bs + c * 16);
      }
    }
    __syncthreads();
#pragma unroll
    for (int ks = 0; ks < 2; ks++) {
      bf16x8 a[4], b[4];
#pragma unroll
      for (int mt = 0; mt < 4; mt++) a[mt] = lds_frag(As, wm + mt * 16 + l16, ks * 4 + quad);
#pragma unroll
      for (int nt = 0; nt < 4; nt++) b[nt] = lds_frag(Bs, wn + nt * 16 + l16, ks * 4 + quad);
#pragma unroll
      for (int mt = 0; mt < 4; mt++)
#pragma unroll
        for (int nt = 0; nt < 4; nt++)
          acc[mt][nt] = __builtin_amdgcn_mfma_f32_16x16x32_bf16(a[mt], b[nt], acc[mt][nt], 0, 0, 0);
    }
  }
#pragma unroll
  for (int nt = 0; nt < 4; nt++) {
    int nloc = nloc0 + wn + nt * 16 + l16;
    float bvv = bias[nloc];
#pragma unroll
    for (int mt = 0; mt < 4; mt++) {
      int row = m0 + wm + mt * 16 + quad * 4;
      if (sel == 2) {
        int d = nloc & 63, h = nloc >> 6;
        int b_ = row >> 11, s = row & 2047;
        int bh = b_ * 16 + h;
        float f0 = acc[mt][nt][0] + bvv, f1 = acc[mt][nt][1] + bvv;
        float f2 = acc[mt][nt][2] + bvv, f3 = acc[mt][nt][3] + bvv;
        uint2v pv = {pack2(f0, f1), pack2(f2, f3)};
        *(uint2v*)((char*)Vt + ((size_t)(bh * 64 + d) * Ss + s) * 2) = pv;
      } else {
        bf16* C = (sel == 0) ? Qp : Kp;
        float scale = (sel == 0) ? SCL : 1.0f;
#pragma unroll
        for (int r = 0; r < 4; r++)
          C[(size_t)(row + r) * 1024 + nloc] = __float2bfloat16((acc[mt][nt][r] + bvv) * scale);
      }
    }
  }
}

// ---------------- flash attention ----------------
// 512 threads, 8 waves: (w&3) = 32-q group, (w>>2) = kb parity. P never touches
// LDS: S^T C-layout (row=quad*4+reg = k, col=lane&15 = q) IS the A-layout of
// mfma_f32_16x16x16_bf16 (A[m=lane&15][k=quad*4+i]) -> PV straight from regs.
// LDS 48K -> 2 blocks/CU = 4 waves/SIMD. l via ones-MFMA; parity partials additive.
__global__ __launch_bounds__(512, 4) void flash_attn(
    const bf16* __restrict__ Q, const bf16* __restrict__ Kp,
    const bf16* __restrict__ Vt, bf16* __restrict__ O) {
  __shared__ char lds[48 * 1024];
  // 0-16K: Qs [q128][d64]; 16-48K: Ks0 Vs0 Ks1 Vs1 (8K each)
  int tid = threadIdx.x, lane = tid & 63, w = tid >> 6;
  int quad = lane >> 4, l16 = lane & 15;
  int bx = blockIdx.x;
  int bh = bx & 31, b = bh >> 4, h = bh & 15;
  int q0 = (bx >> 5) * 128;
  int qw = (w & 3) * 32;
  int parity = w >> 2;
  const char* Ksb = lds + 16 * 1024 + parity * 16 * 1024;
  const char* Vsb = Ksb + 8 * 1024;

#pragma unroll
  for (int i = 0; i < 2; i++) {
    int c = i * 512 + tid;
    int row = c >> 3, cc = c & 7;
    int gcol = (cc ^ (row & 7)) * 16;
    gl_lds16((const char*)Q + ((size_t)(b * Ss + q0 + row) * Dd + h * 64) * 2 + gcol, lds + c * 16);
  }

  f32x4 o_acc[2][4] = {};
  f32x4 l_acc[2] = {};
  const short4v ones4 = {(short)0x3F80, (short)0x3F80, (short)0x3F80, (short)0x3F80};

  for (int kb0 = 0; kb0 < Ss / 64; kb0 += 2) {
    __syncthreads();
    {
      int row = tid >> 3, cc = tid & 7;
      int gcol = (cc ^ (row & 7)) * 16;
#pragma unroll
      for (int i = 0; i < 4; i++) {
        int kbb = kb0 + (i >> 1);
        char* dst = lds + 16 * 1024 + i * 8 * 1024 + tid * 16;
        if ((i & 1) == 0)
          gl_lds16((const char*)Kp + ((size_t)(b * Ss + kbb * 64 + row) * Dd + h * 64) * 2 + gcol, dst);
        else
          gl_lds16((const char*)Vt + ((size_t)(bh * 64 + row) * Ss + kbb * 64) * 2 + gcol, dst);
      }
    }
    __syncthreads();

    // S^T = K @ Q^T : s[kt][qt], k = kt*16+quad*4+reg, q = qw+qt*16+l16
    f32x4 s[4][2] = {};
#pragma unroll
    for (int ks = 0; ks < 2; ks++) {
      bf16x8 ak[4], bq[2];
#pragma unroll
      for (int kt = 0; kt < 4; kt++) ak[kt] = lds_frag(Ksb, kt * 16 + l16, ks * 4 + quad);
#pragma unroll
      for (int qt = 0; qt < 2; qt++) bq[qt] = lds_frag(lds, qw + qt * 16 + l16, ks * 4 + quad);
#pragma unroll
      for (int kt = 0; kt < 4; kt++)
#pragma unroll
        for (int qt = 0; qt < 2; qt++)
          s[kt][qt] = __builtin_amdgcn_mfma_f32_16x16x32_bf16(ak[kt], bq[qt], s[kt][qt], 0, 0, 0);
    }

    // exp2 -> A-frags in registers -> PV + l via K=16 MFMA (no P LDS round-trip)
#pragma unroll
    for (int kt = 0; kt < 4; kt++) {
      short4v af[2];
#pragma unroll
      for (int qt = 0; qt < 2; qt++) {
        union { short4v s4; uint2v u2; } u;
        u.u2[0] = pack2(exp2f(s[kt][qt][0]), exp2f(s[kt][qt][1]));
        u.u2[1] = pack2(exp2f(s[kt][qt][2]), exp2f(s[kt][qt][3]));
        af[qt] = u.s4;
      }
#pragma unroll
      for (int nt = 0; nt < 4; nt++) {
        // B-frag: B[k=kt*16+quad*4+i][n=nt*16+l16] = Vs[row=n][col=k]
        int row = nt * 16 + l16;
        int chunk = kt * 2 + (quad >> 1);
        int addr = row * 128 + ((chunk ^ (row & 7)) * 16) + (quad & 1) * 8;
        short4v bfv = *(const short4v*)(Vsb + addr);
#pragma unroll
        for (int qt = 0; qt < 2; qt++)
          o_acc[qt][nt] = __builtin_amdgcn_mfma_f32_16x16x16bf16_1k(af[qt], bfv, o_acc[qt][nt], 0, 0, 0);
      }
#pragma unroll
      for (int qt = 0; qt < 2; qt++)
        l_acc[qt] = __builtin_amdgcn_mfma_f32_16x16x16bf16_1k(af[qt], ones4, l_acc[qt], 0, 0, 0);
    }
  }

  // merge parity partials (additive), normalize, write
  __syncthreads();
  float* Obuf = (float*)lds;                 // [128][64] f32 = 32K (Qs/Ks0/Vs0 dead)
  float* Lbuf = (float*)(lds + 32 * 1024);   // [128] f32 (Ks1 dead)
  if (parity == 1) {
#pragma unroll
    for (int qt = 0; qt < 2; qt++)
#pragma unroll
      for (int r = 0; r < 4; r++) {
        int qrow = qw + qt * 16 + quad * 4 + r;
#pragma unroll
        for (int nt = 0; nt < 4; nt++) Obuf[qrow * 64 + nt * 16 + l16] = o_acc[qt][nt][r];
        Lbuf[qrow] = l_acc[qt][r];
      }
  }
  __syncthreads();
  if (parity == 0) {
#pragma unroll
    for (int qt = 0; qt < 2; qt++)
#pragma unroll
      for (int r = 0; r < 4; r++) {
        int qrow = qw + qt * 16 + quad * 4 + r;
        float inv = 1.0f / (l_acc[qt][r] + Lbuf[qrow]);
        int grow = b * Ss + q0 + qrow;
#pragma unroll
        for (int nt = 0; nt < 4; nt++) {
          float val = (o_acc[qt][nt][r] + Obuf[qrow * 64 + nt * 16 + l16]) * inv;
          O[(size_t)grow * Dd + h * 64 + nt * 16 + l16] = __float2bfloat16(val);
        }
      }
  }
}

// ---------------- output GEMM: 64x64 tiles, 1024 blocks (4/CU) ----------------
__global__ __launch_bounds__(256, 4) void gemm_out(
    const bf16* __restrict__ AO, const bf16* __restrict__ WT,
    const float* __restrict__ bo, float* __restrict__ out) {
  __shared__ char As[64 * 128], Bs[64 * 128];
  const int K = 1024;
  int tid = threadIdx.x, lane = tid & 63, w = tid >> 6;
  int quad = lane >> 4, l16 = lane & 15;
  int xcd = blockIdx.x & 7, slot = blockIdx.x >> 3;  // 0..127
  int mblk = xcd * 8 + (slot & 7);                   // 0..63
  int nblk = slot >> 3;                              // 0..15
  int m0 = mblk * 64, n0 = nblk * 64;
  int wm = (w & 1) * 32, wn = (w >> 1) * 32;
  f32x4 acc[2][2] = {};
  for (int k0 = 0; k0 < K; k0 += 64) {
    __syncthreads();
#pragma unroll
    for (int i = 0; i < 2; i++) {
      int c = i * 256 + tid;
      int row = c >> 3, cc = c & 7;
      int g = (cc ^ (row & 7)) * 16;
      gl_lds16((const char*)AO + ((size_t)(m0 + row) * K + k0) * 2 + g, As + c * 16);
      gl_lds16((const char*)WT + ((size_t)(n0 + row) * K + k0) * 2 + g, Bs + c * 16);
    }
    __syncthreads();
#pragma unroll
    for (int ks = 0; ks < 2; ks++) {
      bf16x8 a[2], b[2];
#pragma unroll
      for (int mt = 0; mt < 2; mt++) a[mt] = lds_frag(As, wm + mt * 16 + l16, ks * 4 + quad);
#pragma unroll
      for (int nt = 0; nt < 2; nt++) b[nt] = lds_frag(Bs, wn + nt * 16 + l16, ks * 4 + quad);
#pragma unroll
      for (int mt = 0; mt < 2; mt++)
#pragma unroll
        for (int nt = 0; nt < 2; nt++)
          acc[mt][nt] = __builtin_amdgcn_mfma_f32_16x16x32_bf16(a[mt], b[nt], acc[mt][nt], 0, 0, 0);
    }
  }
#pragma unroll
  for (int nt = 0; nt < 2; nt++) {
    int col = n0 + wn + nt * 16 + l16;
    float bvv = bo[col];
#pragma unroll
    for (int mt = 0; mt < 2; mt++) {
      int row = m0 + wm + mt * 16 + quad * 4;
#pragma unroll
      for (int r = 0; r < 4; r++)
        out[(size_t)(row + r) * 1024 + col] = acc[mt][nt][r] + bvv;
    }
  }
}

extern "C" void kernel_launch(void* const* d_in, const int* in_sizes, int n_in,
                              void* d_out, int out_size, void* d_ws, size_t ws_size,
                              hipStream_t stream) {
  const float* q  = (const float*)d_in[0];
  const float* k  = (const float*)d_in[1];
  const float* v  = (const float*)d_in[2];
  const float* wq = (const float*)d_in[3];
  const float* bq = (const float*)d_in[4];
  const float* wk = (const float*)d_in[5];
  const float* bk = (const float*)d_in[6];
  const float* wv = (const float*)d_in[7];
  const float* bv = (const float*)d_in[8];
  const float* wo = (const float*)d_in[9];
  const float* bo = (const float*)d_in[10];
  float* out = (float*)d_out;

  // ws: 32 MB.  0-6: wt_qkv  6-8: wto  8-16: Qp->AO  16-24: Kp  24-32: Vt
  // d_out doubles as scratch: Qb (0-8), Kb (8-16) bf16 — dead before gemm_out.
  char* ws = (char*)d_ws;
  const size_t MB = (size_t)1024 * 1024;
  bf16* wtall = (bf16*)(ws + 0 * MB);
  bf16* wtq = wtall;
  bf16* wtk = (bf16*)(ws + 2 * MB);
  bf16* wtv = (bf16*)(ws + 4 * MB);
  bf16* wto = (bf16*)(ws + 6 * MB);
  bf16* Qp  = (bf16*)(ws + 8 * MB);
  bf16* AO  = Qp;
  bf16* Kp  = (bf16*)(ws + 16 * MB);
  bf16* Vt  = (bf16*)(ws + 24 * MB);
  bf16* Qb  = (bf16*)((char*)d_out + 0 * MB);
  bf16* Kb  = (bf16*)((char*)d_out + 8 * MB);

  dim3 tb(64, 4);
  convert_qk<<<4096, 256, 0, stream>>>(q, k, Qb, Kb);
  transpose_w4<<<dim3(16, 16, 4), tb, 0, stream>>>(wq, wk, wv, wo, wtq, wtk, wtv, wto);
  gemm_qkv<<<768, 256, 0, stream>>>(Qb, Kb, v, wtall, bq, bk, bv, Qp, Kp, Vt);
  flash_attn<<<512, 512, 0, stream>>>(Qp, Kp, Vt, AO);
  gemm_out<<<1024, 256, 0, stream>>>(AO, wto, bo, out);
}

// Round 5
// 242.410 us; speedup vs baseline: 1.1008x; 1.0268x over previous
//
#include <hip/hip_runtime.h>
#include <hip/hip_bf16.h>
#include <stdint.h>

#define Bb 2
#define Ss 2048
#define Dd 1024
#define Hh 16

typedef __hip_bfloat16 bf16;
typedef __attribute__((ext_vector_type(8))) short bf16x8;
typedef __attribute__((ext_vector_type(4))) short short4v;
typedef __attribute__((ext_vector_type(4))) float f32x4;
typedef __attribute__((ext_vector_type(4))) unsigned uint4v;
typedef __attribute__((ext_vector_type(2))) unsigned uint2v;

__device__ __forceinline__ void gl_lds16(const void* g, void* l) {
  __builtin_amdgcn_global_load_lds((const __attribute__((address_space(1))) void*)g,
                                   (__attribute__((address_space(3))) void*)l, 16, 0, 0);
}

// two f32 -> packed bf16 pair, round-half-up
__device__ __forceinline__ unsigned pack2(float a, float b) {
  unsigned ua = __builtin_bit_cast(unsigned, a), ub = __builtin_bit_cast(unsigned, b);
  return ((ua + 0x8000u) >> 16) | ((ub + 0x8000u) & 0xffff0000u);
}

// rows are 128B (8 chunks of 16B); logical chunk cl is XOR-swizzled by (row&7)
__device__ __forceinline__ bf16x8 lds_frag(const char* base, int row, int cl) {
  int phys = cl ^ (row & 7);
  return *(const bf16x8*)(base + row * 128 + phys * 16);
}

// ---------------- q,k fp32 -> bf16 (streaming) ----------------
__global__ void convert_qk(const float* __restrict__ q, const float* __restrict__ k,
                           bf16* __restrict__ Qb, bf16* __restrict__ Kb) {
  int sel = blockIdx.x >> 11;
  const float* src = sel ? k : q;
  bf16* dst = sel ? Kb : Qb;
  size_t i = (size_t)(blockIdx.x & 2047) * 256 + threadIdx.x;
  f32x4 v0 = *(const f32x4*)(src + i * 8);
  f32x4 v1 = *(const f32x4*)(src + i * 8 + 4);
  uint4v o = {pack2(v0[0], v0[1]), pack2(v0[2], v0[3]),
              pack2(v1[0], v1[1]), pack2(v1[2], v1[3])};
  *(uint4v*)((char*)dst + i * 16) = o;
}

// ---------------- weight transpose: fp32 [1024,1024] -> bf16 W^T ----------------
__global__ void transpose_w4(const float* w0, const float* w1, const float* w2, const float* w3,
                             bf16* t0, bf16* t1, bf16* t2, bf16* t3) {
  const float* W;
  bf16* T;
  switch (blockIdx.z) {
    case 0: W = w0; T = t0; break;
    case 1: W = w1; T = t1; break;
    case 2: W = w2; T = t2; break;
    default: W = w3; T = t3; break;
  }
  __shared__ bf16 tile[64][65];
  int tx = threadIdx.x, ty = threadIdx.y;
  int r0 = blockIdx.y * 64, c0 = blockIdx.x * 64;
#pragma unroll
  for (int j = 0; j < 16; j++) {
    int r = ty + j * 4;
    tile[r][tx] = __float2bfloat16(W[(size_t)(r0 + r) * 1024 + c0 + tx]);
  }
  __syncthreads();
#pragma unroll
  for (int j = 0; j < 16; j++) {
    int r = ty + j * 4;
    T[(size_t)(c0 + r) * 1024 + r0 + tx] = tile[tx][r];
  }
}

// ---------------- merged QKV GEMM ----------------
// Round-5 change: __launch_bounds__(256,3) -> (256,4).
// acc[4][4] f32x4 = 64 AGPR + 68 arch VGPR = 132 unified regs > 128 cliff
// -> only 2 blocks/CU resident (occupancy 19.7%, MfmaUtil 13.5%). Forcing the
// 128-reg fit (shave 4 addr temps) unlocks 16 waves/CU -> all 3 blocks/CU
// co-resident, latency hidden by TLP.
#define SCL 0.180336878f
__global__ __launch_bounds__(256, 4) void gemm_qkv(
    const bf16* __restrict__ Qb, const bf16* __restrict__ Kb, const float* __restrict__ v,
    const bf16* __restrict__ WTall,
    const float* __restrict__ bq, const float* __restrict__ bk, const float* __restrict__ bv,
    bf16* __restrict__ Qp, bf16* __restrict__ Kp, bf16* __restrict__ Vt) {
  __shared__ char As[128 * 128], Bs[128 * 128];
  const int K = 1024;
  int tid = threadIdx.x, lane = tid & 63, w = tid >> 6;
  int quad = lane >> 4, l16 = lane & 15;
  int xcd = blockIdx.x & 7, slot = blockIdx.x >> 3;
  int pair = xcd * 12 + (slot % 12);
  int nloc_blk = slot / 12;
  int mblk = pair / 3, sel = pair % 3;
  int m0 = mblk * 128;
  int nloc0 = nloc_blk * 128;
  int n0 = sel * 1024 + nloc0;
  const bf16* Ab = (sel == 0) ? Qb : Kb;
  const float* bias = (sel == 0) ? bq : (sel == 1) ? bk : bv;
  int wm = (w >> 1) * 64, wn = (w & 1) * 64;
  f32x4 acc[4][4] = {};
  for (int k0 = 0; k0 < K; k0 += 64) {
    __syncthreads();
    if (sel < 2) {
#pragma unroll
      for (int i = 0; i < 4; i++) {
        int c = i * 256 + tid;
        int row = c >> 3, cc = c & 7;
        int g = (cc ^ (row & 7)) * 16;
        gl_lds16((const char*)Ab + ((size_t)(m0 + row) * K + k0) * 2 + g, As + c * 16);
        gl_lds16((const char*)WTall + ((size_t)(n0 + row) * K + k0) * 2 + g, Bs + c * 16);
      }
    } else {
#pragma unroll
      for (int i = 0; i < 4; i++) {
        int c = i * 256 + tid;
        int row = c >> 3, cc = c & 7;
        int g = cc ^ (row & 7);
        const float* src = v + (size_t)(m0 + row) * K + k0 + g * 8;
        f32x4 v0 = *(const f32x4*)src;
        f32x4 v1 = *(const f32x4*)(src + 4);
        uint4v o = {pack2(v0[0], v0[1]), pack2(v0[2], v0[3]),
                    pack2(v1[0], v1[1]), pack2(v1[2], v1[3])};
        *(uint4v*)(As + c * 16) = o;
        gl_lds16((const char*)WTall + ((size_t)(n0 + row) * K + k0) * 2 + g * 16, Bs + c * 16);
      }
    }
    __syncthreads();
#pragma unroll
    for (int ks = 0; ks < 2; ks++) {
      bf16x8 a[4], b[4];
#pragma unroll
      for (int mt = 0; mt < 4; mt++) a[mt] = lds_frag(As, wm + mt * 16 + l16, ks * 4 + quad);
#pragma unroll
      for (int nt = 0; nt < 4; nt++) b[nt] = lds_frag(Bs, wn + nt * 16 + l16, ks * 4 + quad);
#pragma unroll
      for (int mt = 0; mt < 4; mt++)
#pragma unroll
        for (int nt = 0; nt < 4; nt++)
          acc[mt][nt] = __builtin_amdgcn_mfma_f32_16x16x32_bf16(a[mt], b[nt], acc[mt][nt], 0, 0, 0);
    }
  }
#pragma unroll
  for (int nt = 0; nt < 4; nt++) {
    int nloc = nloc0 + wn + nt * 16 + l16;
    float bvv = bias[nloc];
#pragma unroll
    for (int mt = 0; mt < 4; mt++) {
      int row = m0 + wm + mt * 16 + quad * 4;
      if (sel == 2) {
        int d = nloc & 63, h = nloc >> 6;
        int b_ = row >> 11, s = row & 2047;
        int bh = b_ * 16 + h;
        float f0 = acc[mt][nt][0] + bvv, f1 = acc[mt][nt][1] + bvv;
        float f2 = acc[mt][nt][2] + bvv, f3 = acc[mt][nt][3] + bvv;
        uint2v pv = {pack2(f0, f1), pack2(f2, f3)};
        *(uint2v*)((char*)Vt + ((size_t)(bh * 64 + d) * Ss + s) * 2) = pv;
      } else {
        bf16* C = (sel == 0) ? Qp : Kp;
        float scale = (sel == 0) ? SCL : 1.0f;
#pragma unroll
        for (int r = 0; r < 4; r++)
          C[(size_t)(row + r) * 1024 + nloc] = __float2bfloat16((acc[mt][nt][r] + bvv) * scale);
      }
    }
  }
}

// ---------------- flash attention ----------------
// 512 threads, 8 waves: (w&3) = 32-q group, (w>>2) = kb parity. P never touches
// LDS: S^T C-layout (row=quad*4+reg = k, col=lane&15 = q) IS the A-layout of
// mfma_f32_16x16x16_bf16 (A[m=lane&15][k=quad*4+i]) -> PV straight from regs.
// LDS 48K -> 2 blocks/CU = 4 waves/SIMD. l via ones-MFMA; parity partials additive.
__global__ __launch_bounds__(512, 4) void flash_attn(
    const bf16* __restrict__ Q, const bf16* __restrict__ Kp,
    const bf16* __restrict__ Vt, bf16* __restrict__ O) {
  __shared__ char lds[48 * 1024];
  // 0-16K: Qs [q128][d64]; 16-48K: Ks0 Vs0 Ks1 Vs1 (8K each)
  int tid = threadIdx.x, lane = tid & 63, w = tid >> 6;
  int quad = lane >> 4, l16 = lane & 15;
  int bx = blockIdx.x;
  int bh = bx & 31, b = bh >> 4, h = bh & 15;
  int q0 = (bx >> 5) * 128;
  int qw = (w & 3) * 32;
  int parity = w >> 2;
  const char* Ksb = lds + 16 * 1024 + parity * 16 * 1024;
  const char* Vsb = Ksb + 8 * 1024;

#pragma unroll
  for (int i = 0; i < 2; i++) {
    int c = i * 512 + tid;
    int row = c >> 3, cc = c & 7;
    int gcol = (cc ^ (row & 7)) * 16;
    gl_lds16((const char*)Q + ((size_t)(b * Ss + q0 + row) * Dd + h * 64) * 2 + gcol, lds + c * 16);
  }

  f32x4 o_acc[2][4] = {};
  f32x4 l_acc[2] = {};
  const short4v ones4 = {(short)0x3F80, (short)0x3F80, (short)0x3F80, (short)0x3F80};

  for (int kb0 = 0; kb0 < Ss / 64; kb0 += 2) {
    __syncthreads();
    {
      int row = tid >> 3, cc = tid & 7;
      int gcol = (cc ^ (row & 7)) * 16;
#pragma unroll
      for (int i = 0; i < 4; i++) {
        int kbb = kb0 + (i >> 1);
        char* dst = lds + 16 * 1024 + i * 8 * 1024 + tid * 16;
        if ((i & 1) == 0)
          gl_lds16((const char*)Kp + ((size_t)(b * Ss + kbb * 64 + row) * Dd + h * 64) * 2 + gcol, dst);
        else
          gl_lds16((const char*)Vt + ((size_t)(bh * 64 + row) * Ss + kbb * 64) * 2 + gcol, dst);
      }
    }
    __syncthreads();

    // S^T = K @ Q^T : s[kt][qt], k = kt*16+quad*4+reg, q = qw+qt*16+l16
    f32x4 s[4][2] = {};
#pragma unroll
    for (int ks = 0; ks < 2; ks++) {
      bf16x8 ak[4], bq[2];
#pragma unroll
      for (int kt = 0; kt < 4; kt++) ak[kt] = lds_frag(Ksb, kt * 16 + l16, ks * 4 + quad);
#pragma unroll
      for (int qt = 0; qt < 2; qt++) bq[qt] = lds_frag(lds, qw + qt * 16 + l16, ks * 4 + quad);
#pragma unroll
      for (int kt = 0; kt < 4; kt++)
#pragma unroll
        for (int qt = 0; qt < 2; qt++)
          s[kt][qt] = __builtin_amdgcn_mfma_f32_16x16x32_bf16(ak[kt], bq[qt], s[kt][qt], 0, 0, 0);
    }

    // exp2 -> A-frags in registers -> PV + l via K=16 MFMA (no P LDS round-trip)
#pragma unroll
    for (int kt = 0; kt < 4; kt++) {
      short4v af[2];
#pragma unroll
      for (int qt = 0; qt < 2; qt++) {
        union { short4v s4; uint2v u2; } u;
        u.u2[0] = pack2(exp2f(s[kt][qt][0]), exp2f(s[kt][qt][1]));
        u.u2[1] = pack2(exp2f(s[kt][qt][2]), exp2f(s[kt][qt][3]));
        af[qt] = u.s4;
      }
#pragma unroll
      for (int nt = 0; nt < 4; nt++) {
        // B-frag: B[k=kt*16+quad*4+i][n=nt*16+l16] = Vs[row=n][col=k]
        int row = nt * 16 + l16;
        int chunk = kt * 2 + (quad >> 1);
        int addr = row * 128 + ((chunk ^ (row & 7)) * 16) + (quad & 1) * 8;
        short4v bfv = *(const short4v*)(Vsb + addr);
#pragma unroll
        for (int qt = 0; qt < 2; qt++)
          o_acc[qt][nt] = __builtin_amdgcn_mfma_f32_16x16x16bf16_1k(af[qt], bfv, o_acc[qt][nt], 0, 0, 0);
      }
#pragma unroll
      for (int qt = 0; qt < 2; qt++)
        l_acc[qt] = __builtin_amdgcn_mfma_f32_16x16x16bf16_1k(af[qt], ones4, l_acc[qt], 0, 0, 0);
    }
  }

  // merge parity partials (additive), normalize, write
  __syncthreads();
  float* Obuf = (float*)lds;                 // [128][64] f32 = 32K (Qs/Ks0/Vs0 dead)
  float* Lbuf = (float*)(lds + 32 * 1024);   // [128] f32 (Ks1 dead)
  if (parity == 1) {
#pragma unroll
    for (int qt = 0; qt < 2; qt++)
#pragma unroll
      for (int r = 0; r < 4; r++) {
        int qrow = qw + qt * 16 + quad * 4 + r;
#pragma unroll
        for (int nt = 0; nt < 4; nt++) Obuf[qrow * 64 + nt * 16 + l16] = o_acc[qt][nt][r];
        Lbuf[qrow] = l_acc[qt][r];
      }
  }
  __syncthreads();
  if (parity == 0) {
#pragma unroll
    for (int qt = 0; qt < 2; qt++)
#pragma unroll
      for (int r = 0; r < 4; r++) {
        int qrow = qw + qt * 16 + quad * 4 + r;
        float inv = 1.0f / (l_acc[qt][r] + Lbuf[qrow]);
        int grow = b * Ss + q0 + qrow;
#pragma unroll
        for (int nt = 0; nt < 4; nt++) {
          float val = (o_acc[qt][nt][r] + Obuf[qrow * 64 + nt * 16 + l16]) * inv;
          O[(size_t)grow * Dd + h * 64 + nt * 16 + l16] = __float2bfloat16(val);
        }
      }
  }
}

// ---------------- output GEMM: 64x64 tiles, 1024 blocks (4/CU) ----------------
__global__ __launch_bounds__(256, 4) void gemm_out(
    const bf16* __restrict__ AO, const bf16* __restrict__ WT,
    const float* __restrict__ bo, float* __restrict__ out) {
  __shared__ char As[64 * 128], Bs[64 * 128];
  const int K = 1024;
  int tid = threadIdx.x, lane = tid & 63, w = tid >> 6;
  int quad = lane >> 4, l16 = lane & 15;
  int xcd = blockIdx.x & 7, slot = blockIdx.x >> 3;  // 0..127
  int mblk = xcd * 8 + (slot & 7);                   // 0..63
  int nblk = slot >> 3;                              // 0..15
  int m0 = mblk * 64, n0 = nblk * 64;
  int wm = (w & 1) * 32, wn = (w >> 1) * 32;
  f32x4 acc[2][2] = {};
  for (int k0 = 0; k0 < K; k0 += 64) {
    __syncthreads();
#pragma unroll
    for (int i = 0; i < 2; i++) {
      int c = i * 256 + tid;
      int row = c >> 3, cc = c & 7;
      int g = (cc ^ (row & 7)) * 16;
      gl_lds16((const char*)AO + ((size_t)(m0 + row) * K + k0) * 2 + g, As + c * 16);
      gl_lds16((const char*)WT + ((size_t)(n0 + row) * K + k0) * 2 + g, Bs + c * 16);
    }
    __syncthreads();
#pragma unroll
    for (int ks = 0; ks < 2; ks++) {
      bf16x8 a[2], b[2];
#pragma unroll
      for (int mt = 0; mt < 2; mt++) a[mt] = lds_frag(As, wm + mt * 16 + l16, ks * 4 + quad);
#pragma unroll
      for (int nt = 0; nt < 2; nt++) b[nt] = lds_frag(Bs, wn + nt * 16 + l16, ks * 4 + quad);
#pragma unroll
      for (int mt = 0; mt < 2; mt++)
#pragma unroll
        for (int nt = 0; nt < 2; nt++)
          acc[mt][nt] = __builtin_amdgcn_mfma_f32_16x16x32_bf16(a[mt], b[nt], acc[mt][nt], 0, 0, 0);
    }
  }
#pragma unroll
  for (int nt = 0; nt < 2; nt++) {
    int col = n0 + wn + nt * 16 + l16;
    float bvv = bo[col];
#pragma unroll
    for (int mt = 0; mt < 2; mt++) {
      int row = m0 + wm + mt * 16 + quad * 4;
#pragma unroll
      for (int r = 0; r < 4; r++)
        out[(size_t)(row + r) * 1024 + col] = acc[mt][nt][r] + bvv;
    }
  }
}

extern "C" void kernel_launch(void* const* d_in, const int* in_sizes, int n_in,
                              void* d_out, int out_size, void* d_ws, size_t ws_size,
                              hipStream_t stream) {
  const float* q  = (const float*)d_in[0];
  const float* k  = (const float*)d_in[1];
  const float* v  = (const float*)d_in[2];
  const float* wq = (const float*)d_in[3];
  const float* bq = (const float*)d_in[4];
  const float* wk = (const float*)d_in[5];
  const float* bk = (const float*)d_in[6];
  const float* wv = (const float*)d_in[7];
  const float* bv = (const float*)d_in[8];
  const float* wo = (const float*)d_in[9];
  const float* bo = (const float*)d_in[10];
  float* out = (float*)d_out;

  // ws: 32 MB.  0-6: wt_qkv  6-8: wto  8-16: Qp->AO  16-24: Kp  24-32: Vt
  // d_out doubles as scratch: Qb (0-8), Kb (8-16) bf16 — dead before gemm_out.
  char* ws = (char*)d_ws;
  const size_t MB = (size_t)1024 * 1024;
  bf16* wtall = (bf16*)(ws + 0 * MB);
  bf16* wtq = wtall;
  bf16* wtk = (bf16*)(ws + 2 * MB);
  bf16* wtv = (bf16*)(ws + 4 * MB);
  bf16* wto = (bf16*)(ws + 6 * MB);
  bf16* Qp  = (bf16*)(ws + 8 * MB);
  bf16* AO  = Qp;
  bf16* Kp  = (bf16*)(ws + 16 * MB);
  bf16* Vt  = (bf16*)(ws + 24 * MB);
  bf16* Qb  = (bf16*)((char*)d_out + 0 * MB);
  bf16* Kb  = (bf16*)((char*)d_out + 8 * MB);

  dim3 tb(64, 4);
  convert_qk<<<4096, 256, 0, stream>>>(q, k, Qb, Kb);
  transpose_w4<<<dim3(16, 16, 4), tb, 0, stream>>>(wq, wk, wv, wo, wtq, wtk, wtv, wto);
  gemm_qkv<<<768, 256, 0, stream>>>(Qb, Kb, v, wtall, bq, bk, bv, Qp, Kp, Vt);
  flash_attn<<<512, 512, 0, stream>>>(Qp, Kp, Vt, AO);
  gemm_out<<<1024, 256, 0, stream>>>(AO, wto, bo, out);
}